// Round 2
// baseline (1867.657 us; speedup 1.0000x reference)
//
#include <hip/hip_runtime.h>
#include <hip/hip_bf16.h>

#define B_ 2
#define L_ 2048
#define E_ 2048
#define H_ 16
#define KVH_ 4
#define HD_ 128
#define WIN_ 512
#define REP_ (H_ / KVH_)
#define SCALE_ 0.08838834764831843f

// ---------------- fp32 tiled GEMM: C = A @ B ----------------
// A row-major [M,K], B row-major [K,N]. M%64==0, N%64==0, K%16==0.
#define TM 64
#define TN 64
#define TK 16

__global__ __launch_bounds__(256) void gemm_f32(
        const float* __restrict__ A, const float* __restrict__ Bm,
        float* __restrict__ C, int M, int N, int K) {
    __shared__ float As[TK][TM + 4];   // A tile transposed: As[k][m]
    __shared__ float Bs[TK][TN + 4];   // Bs[k][n]
    const int t  = threadIdx.x;
    const int bm = blockIdx.y * TM;
    const int bn = blockIdx.x * TN;
    const int tx = t & 15, ty = t >> 4;
    const int arow = t >> 2, acol = (t & 3) * 4;   // A: 64 rows x 16 cols, float4 each
    const int bidx = t * 4;
    const int brow = bidx >> 6, bcol = bidx & 63;  // B: 16 rows x 64 cols
    float acc[4][4] = {};
    for (int k0 = 0; k0 < K; k0 += TK) {
        float4 av = *(const float4*)&A[(size_t)(bm + arow) * K + k0 + acol];
        As[acol + 0][arow] = av.x;
        As[acol + 1][arow] = av.y;
        As[acol + 2][arow] = av.z;
        As[acol + 3][arow] = av.w;
        *(float4*)&Bs[brow][bcol] =
            *(const float4*)&Bm[(size_t)(k0 + brow) * N + bn + bcol];
        __syncthreads();
        #pragma unroll
        for (int kk = 0; kk < TK; ++kk) {
            float4 a4 = *(const float4*)&As[kk][ty * 4];
            float4 b4 = *(const float4*)&Bs[kk][tx * 4];
            float a[4] = {a4.x, a4.y, a4.z, a4.w};
            float b[4] = {b4.x, b4.y, b4.z, b4.w};
            #pragma unroll
            for (int i = 0; i < 4; ++i)
                #pragma unroll
                for (int j = 0; j < 4; ++j)
                    acc[i][j] += a[i] * b[j];
        }
        __syncthreads();
    }
    #pragma unroll
    for (int i = 0; i < 4; ++i) {
        float4 c4 = make_float4(acc[i][0], acc[i][1], acc[i][2], acc[i][3]);
        *(float4*)&C[(size_t)(bm + ty * 4 + i) * N + bn + tx * 4] = c4;
    }
}

// ---------------- fp32 windowed flash attention ----------------
// q: [B*L, H*HD], k/v: [B*L, KVH*HD], out: [B*L, H*HD] (may alias q).
// One block per (q-tile of 32 rows, b*H+h). Keys in [max(0,i0-WIN), i0+31].
#define QB 32
#define KB 32

__global__ __launch_bounds__(256) void attn_swa(
        const float* __restrict__ qb, const float* __restrict__ kb,
        const float* __restrict__ vb, float* __restrict__ ob) {
    __shared__ float qs[QB][HD_ + 4];
    __shared__ float ks[KB][HD_ + 4];
    __shared__ float vs[KB][HD_];
    __shared__ float sc[QB][KB + 1];

    const int t  = threadIdx.x;
    const int bh = blockIdx.y;
    const int b  = bh / H_, h = bh % H_;
    const int kh = h / REP_;
    const int i0 = blockIdx.x * QB;

    // stage the 32 q rows for this head
    for (int idx = t; idx < QB * HD_ / 4; idx += 256) {
        int r = idx >> 5;
        int c = (idx & 31) * 4;
        *(float4*)&qs[r][c] =
            *(const float4*)&qb[((size_t)(b * L_ + i0 + r) * H_ + h) * HD_ + c];
    }

    const int r  = t >> 3;        // query row 0..31 (8 lanes per row)
    const int g  = t & 7;         // lane within row-group
    const int cg = g * 4;         // column base; thread owns cols cg+32*qi+{0..3}
    float4 o4[4];
    #pragma unroll
    for (int qi = 0; qi < 4; ++qi) o4[qi] = make_float4(0.f, 0.f, 0.f, 0.f);
    float mreg = -1e30f, lreg = 0.f;

    int jlo = i0 - WIN_;
    if (jlo < 0) jlo = 0;
    const int nch = (i0 + QB - jlo) / KB;   // always exact (i0 % 32 == 0)
    const int i = i0 + r;

    for (int ch = 0; ch < nch; ++ch) {
        const int jb = jlo + ch * KB;
        // stage K/V chunk
        for (int idx = t; idx < KB * HD_ / 4; idx += 256) {
            int kk = idx >> 5;
            int c  = (idx & 31) * 4;
            size_t base = ((size_t)(b * L_ + jb + kk) * KVH_ + kh) * HD_ + c;
            *(float4*)&ks[kk][c] = *(const float4*)&kb[base];
            *(float4*)&vs[kk][c] = *(const float4*)&vb[base];
        }
        __syncthreads();

        // scores: this thread does row r, key cols g+8x (x=0..3)
        float sm[4] = {0.f, 0.f, 0.f, 0.f};
        for (int d = 0; d < HD_; d += 4) {
            float4 qv = *(const float4*)&qs[r][d];
            #pragma unroll
            for (int x = 0; x < 4; ++x) {
                float4 kv = *(const float4*)&ks[g + 8 * x][d];
                sm[x] += qv.x * kv.x + qv.y * kv.y + qv.z * kv.z + qv.w * kv.w;
            }
        }
        float lmax = -1e30f;
        #pragma unroll
        for (int x = 0; x < 4; ++x) {
            int j = jb + g + 8 * x;
            sm[x] = (j <= i && j >= i - WIN_) ? sm[x] * SCALE_ : -1e30f;
            lmax = fmaxf(lmax, sm[x]);
        }
        lmax = fmaxf(lmax, __shfl_xor(lmax, 1));
        lmax = fmaxf(lmax, __shfl_xor(lmax, 2));
        lmax = fmaxf(lmax, __shfl_xor(lmax, 4));
        float mnew = fmaxf(mreg, lmax);
        float alpha, psum = 0.f, p[4];
        if (mnew <= -1e29f) {            // whole window masked so far
            alpha = 1.f;
            #pragma unroll
            for (int x = 0; x < 4; ++x) p[x] = 0.f;
        } else {
            alpha = __expf(mreg - mnew);
            #pragma unroll
            for (int x = 0; x < 4; ++x) { p[x] = __expf(sm[x] - mnew); psum += p[x]; }
            mreg = mnew;
        }
        psum += __shfl_xor(psum, 1);
        psum += __shfl_xor(psum, 2);
        psum += __shfl_xor(psum, 4);
        lreg = lreg * alpha + psum;
        #pragma unroll
        for (int x = 0; x < 4; ++x) sc[r][g + 8 * x] = p[x];
        #pragma unroll
        for (int qi = 0; qi < 4; ++qi) {
            o4[qi].x *= alpha; o4[qi].y *= alpha;
            o4[qi].z *= alpha; o4[qi].w *= alpha;
        }
        __syncthreads();

        // PV: o[cg+32*qi+{0..3}] += sum_kk P[r][kk] * V[kk][col]
        #pragma unroll 8
        for (int kk = 0; kk < KB; ++kk) {
            float p_ = sc[r][kk];
            #pragma unroll
            for (int qi = 0; qi < 4; ++qi) {
                const float4 v4 = *(const float4*)&vs[kk][cg + 32 * qi];
                o4[qi].x += p_ * v4.x;
                o4[qi].y += p_ * v4.y;
                o4[qi].z += p_ * v4.z;
                o4[qi].w += p_ * v4.w;
            }
        }
        __syncthreads();
    }

    const float inv = 1.f / lreg;
    #pragma unroll
    for (int qi = 0; qi < 4; ++qi) {
        float4 c4 = make_float4(o4[qi].x * inv, o4[qi].y * inv,
                                o4[qi].z * inv, o4[qi].w * inv);
        *(float4*)&ob[((size_t)(b * L_ + i0 + r) * H_ + h) * HD_ + cg + 32 * qi] = c4;
    }
}

extern "C" void kernel_launch(void* const* d_in, const int* in_sizes, int n_in,
                              void* d_out, int out_size, void* d_ws, size_t ws_size,
                              hipStream_t stream) {
    const float* x  = (const float*)d_in[0];
    const float* Wq = (const float*)d_in[1];
    const float* Wk = (const float*)d_in[2];
    const float* Wv = (const float*)d_in[3];
    const float* Wo = (const float*)d_in[4];
    float* out = (float*)d_out;

    float* ws   = (float*)d_ws;
    float* qbuf = ws;                      // [4096, 2048] — reused as attn output
    float* kbuf = qbuf + (size_t)B_ * L_ * H_ * HD_;     // [4096, 512]
    float* vbuf = kbuf + (size_t)B_ * L_ * KVH_ * HD_;   // [4096, 512]

    const int M = B_ * L_;                 // 4096
    dim3 blk(256);

    // projections
    gemm_f32<<<dim3((H_ * HD_) / TN, M / TM), blk, 0, stream>>>(
        x, Wq, qbuf, M, H_ * HD_, E_);
    gemm_f32<<<dim3((KVH_ * HD_) / TN, M / TM), blk, 0, stream>>>(
        x, Wk, kbuf, M, KVH_ * HD_, E_);
    gemm_f32<<<dim3((KVH_ * HD_) / TN, M / TM), blk, 0, stream>>>(
        x, Wv, vbuf, M, KVH_ * HD_, E_);

    // windowed attention (writes back into qbuf — safe: each block reads
    // exactly the q rows/cols it later overwrites)
    attn_swa<<<dim3(L_ / QB, B_ * H_), blk, 0, stream>>>(qbuf, kbuf, vbuf, qbuf);

    // output projection
    gemm_f32<<<dim3(E_ / TN, M / TM), blk, 0, stream>>>(
        qbuf, Wo, out, M, E_, E_);
}

// Round 3
// 880.295 us; speedup vs baseline: 2.1216x; 2.1216x over previous
//
#include <hip/hip_runtime.h>
#include <hip/hip_bf16.h>

#define B_ 2
#define L_ 2048
#define E_ 2048
#define H_ 16
#define KVH_ 4
#define HD_ 128
#define WIN_ 512
#define REP_ (H_ / KVH_)
#define SCALE_ 0.08838834764831843f

typedef __bf16 bf16x8 __attribute__((ext_vector_type(8)));
typedef float f32x4 __attribute__((ext_vector_type(4)));

__device__ __forceinline__ unsigned short f2bf(float x) {
    __hip_bfloat16 h = __float2bfloat16(x);
    return *reinterpret_cast<unsigned short*>(&h);
}

__device__ __forceinline__ void gload_lds16(const unsigned short* g, unsigned short* l) {
    __builtin_amdgcn_global_load_lds(
        (const __attribute__((address_space(1))) void*)g,
        (__attribute__((address_space(3))) void*)l,
        16, 0, 0);
}

// ---------------- fp32 -> bf16 elementwise convert (float4/ushort4) --------
__global__ __launch_bounds__(256) void conv_f32_bf16(
        const float* __restrict__ in, unsigned short* __restrict__ out, int n4) {
    int i = blockIdx.x * 256 + threadIdx.x;
    if (i >= n4) return;
    float4 v = reinterpret_cast<const float4*>(in)[i];
    ushort4 o;
    o.x = f2bf(v.x); o.y = f2bf(v.y); o.z = f2bf(v.z); o.w = f2bf(v.w);
    reinterpret_cast<ushort4*>(out)[i] = o;
}

// ---------------- fp32 [K][N] -> bf16 [N][K] transpose ----------------------
__global__ __launch_bounds__(256) void transpose_f32_bf16(
        const float* __restrict__ W, unsigned short* __restrict__ WT,
        int K, int N, int wts) {
    __shared__ unsigned short tile[32][33];
    const int t = threadIdx.x;
    const int r = t >> 5, c = t & 31;
    const int k0 = blockIdx.y * 32, n0 = blockIdx.x * 32;
    #pragma unroll
    for (int i = 0; i < 4; ++i)
        tile[r + i * 8][c] = f2bf(W[(size_t)(k0 + r + i * 8) * N + n0 + c]);
    __syncthreads();
    #pragma unroll
    for (int i = 0; i < 4; ++i)
        WT[(size_t)(n0 + r + i * 8) * wts + k0 + c] = tile[c][r + i * 8];
}

// ---------------- bf16 MFMA GEMM: C = A @ BT^T (m97 structure) --------------
// A [M][K] bf16 row-major, BT [N][K] bf16 row-major, C [M][N] fp32.
// 128x128 tile, BK=32, 256 threads = 4 waves in 2x2, 16x16x32 MFMA, 4x4 acc.
__global__ __launch_bounds__(256) void gemm_bt_bf16(
        const unsigned short* __restrict__ A, const unsigned short* __restrict__ BT,
        float* __restrict__ C, int M, int N, int K) {
    __shared__ __attribute__((aligned(16))) unsigned short As[128 * 32];
    __shared__ __attribute__((aligned(16))) unsigned short Bs[128 * 32];
    const int t  = threadIdx.x;
    const int wv = t >> 6, ln = t & 63;
    const int wr = wv >> 1, wc = wv & 1;
    const int bm = blockIdx.y * 128, bn = blockIdx.x * 128;
    const int lrow = ln & 15;            // fragment row/col within 16
    const int lk8  = (ln >> 4) * 8;      // fragment K-offset (8 contiguous)

    f32x4 acc[4][4];
    const f32x4 z = {0.f, 0.f, 0.f, 0.f};
    #pragma unroll
    for (int m = 0; m < 4; ++m)
        #pragma unroll
        for (int n = 0; n < 4; ++n) acc[m][n] = z;

    for (int k0 = 0; k0 < K; k0 += 32) {
        // stage 128x32 A-tile and B-tile: chunk = seg*256+t <-> 16B each,
        // LDS dest linear (wave-uniform base + lane*16 per global_load_lds)
        #pragma unroll
        for (int seg = 0; seg < 2; ++seg) {
            const int chunk = seg * 256 + t;
            const int row = chunk >> 2, c8 = (chunk & 3) * 8;
            const int lbase = (seg * 256 + wv * 64) * 8;  // element offset
            gload_lds16(A  + (size_t)(bm + row) * K + k0 + c8, &As[lbase]);
            gload_lds16(BT + (size_t)(bn + row) * K + k0 + c8, &Bs[lbase]);
        }
        __syncthreads();
        bf16x8 af[4], bfr[4];
        #pragma unroll
        for (int m = 0; m < 4; ++m)
            af[m] = *reinterpret_cast<const bf16x8*>(
                &As[(wr * 64 + m * 16 + lrow) * 32 + lk8]);
        #pragma unroll
        for (int n = 0; n < 4; ++n)
            bfr[n] = *reinterpret_cast<const bf16x8*>(
                &Bs[(wc * 64 + n * 16 + lrow) * 32 + lk8]);
        #pragma unroll
        for (int m = 0; m < 4; ++m)
            #pragma unroll
            for (int n = 0; n < 4; ++n)
                acc[m][n] = __builtin_amdgcn_mfma_f32_16x16x32_bf16(
                    af[m], bfr[n], acc[m][n], 0, 0, 0);
        __syncthreads();
    }
    // C/D layout (m89-verified): col = lane&15, row = (lane>>4)*4 + reg
    const int crq = (ln >> 4) * 4;
    #pragma unroll
    for (int m = 0; m < 4; ++m)
        #pragma unroll
        for (int n = 0; n < 4; ++n)
            #pragma unroll
            for (int r = 0; r < 4; ++r)
                C[(size_t)(bm + wr * 64 + m * 16 + crq + r) * N
                  + bn + wc * 64 + n * 16 + lrow] = acc[m][n][r];
}

// ---------------- fp32 windowed flash attention (unchanged core) ------------
#define QB 32
#define KB 32

__global__ __launch_bounds__(256) void attn_swa(
        const float* __restrict__ qb, const float* __restrict__ kb,
        const float* __restrict__ vb, float* __restrict__ ob, int kvs) {
    __shared__ float qs[QB][HD_ + 4];
    __shared__ float ks[KB][HD_ + 4];
    __shared__ float vs[KB][HD_];
    __shared__ float sc[QB][KB + 1];

    const int t  = threadIdx.x;
    const int bh = blockIdx.y;
    const int b  = bh / H_, h = bh % H_;
    const int kh = h / REP_;
    const int i0 = blockIdx.x * QB;

    for (int idx = t; idx < QB * HD_ / 4; idx += 256) {
        int r = idx >> 5;
        int c = (idx & 31) * 4;
        *(float4*)&qs[r][c] =
            *(const float4*)&qb[((size_t)(b * L_ + i0 + r) * H_ + h) * HD_ + c];
    }

    const int r  = t >> 3;
    const int g  = t & 7;
    const int cg = g * 4;
    float4 o4[4];
    #pragma unroll
    for (int qi = 0; qi < 4; ++qi) o4[qi] = make_float4(0.f, 0.f, 0.f, 0.f);
    float mreg = -1e30f, lreg = 0.f;

    int jlo = i0 - WIN_;
    if (jlo < 0) jlo = 0;
    const int nch = (i0 + QB - jlo) / KB;
    const int i = i0 + r;

    for (int ch = 0; ch < nch; ++ch) {
        const int jb = jlo + ch * KB;
        for (int idx = t; idx < KB * HD_ / 4; idx += 256) {
            int kk = idx >> 5;
            int c  = (idx & 31) * 4;
            size_t base = (size_t)(b * L_ + jb + kk) * kvs + kh * HD_ + c;
            *(float4*)&ks[kk][c] = *(const float4*)&kb[base];
            *(float4*)&vs[kk][c] = *(const float4*)&vb[base];
        }
        __syncthreads();

        float sm[4] = {0.f, 0.f, 0.f, 0.f};
        for (int d = 0; d < HD_; d += 4) {
            float4 qv = *(const float4*)&qs[r][d];
            #pragma unroll
            for (int x = 0; x < 4; ++x) {
                float4 kv = *(const float4*)&ks[g + 8 * x][d];
                sm[x] += qv.x * kv.x + qv.y * kv.y + qv.z * kv.z + qv.w * kv.w;
            }
        }
        float lmax = -1e30f;
        #pragma unroll
        for (int x = 0; x < 4; ++x) {
            int j = jb + g + 8 * x;
            sm[x] = (j <= i && j >= i - WIN_) ? sm[x] * SCALE_ : -1e30f;
            lmax = fmaxf(lmax, sm[x]);
        }
        lmax = fmaxf(lmax, __shfl_xor(lmax, 1));
        lmax = fmaxf(lmax, __shfl_xor(lmax, 2));
        lmax = fmaxf(lmax, __shfl_xor(lmax, 4));
        float mnew = fmaxf(mreg, lmax);
        float alpha, psum = 0.f, p[4];
        if (mnew <= -1e29f) {
            alpha = 1.f;
            #pragma unroll
            for (int x = 0; x < 4; ++x) p[x] = 0.f;
        } else {
            alpha = __expf(mreg - mnew);
            #pragma unroll
            for (int x = 0; x < 4; ++x) { p[x] = __expf(sm[x] - mnew); psum += p[x]; }
            mreg = mnew;
        }
        psum += __shfl_xor(psum, 1);
        psum += __shfl_xor(psum, 2);
        psum += __shfl_xor(psum, 4);
        lreg = lreg * alpha + psum;
        #pragma unroll
        for (int x = 0; x < 4; ++x) sc[r][g + 8 * x] = p[x];
        #pragma unroll
        for (int qi = 0; qi < 4; ++qi) {
            o4[qi].x *= alpha; o4[qi].y *= alpha;
            o4[qi].z *= alpha; o4[qi].w *= alpha;
        }
        __syncthreads();

        #pragma unroll 8
        for (int kk = 0; kk < KB; ++kk) {
            float p_ = sc[r][kk];
            #pragma unroll
            for (int qi = 0; qi < 4; ++qi) {
                const float4 v4 = *(const float4*)&vs[kk][cg + 32 * qi];
                o4[qi].x += p_ * v4.x;
                o4[qi].y += p_ * v4.y;
                o4[qi].z += p_ * v4.z;
                o4[qi].w += p_ * v4.w;
            }
        }
        __syncthreads();
    }

    const float inv = 1.f / lreg;
    #pragma unroll
    for (int qi = 0; qi < 4; ++qi) {
        float4 c4 = make_float4(o4[qi].x * inv, o4[qi].y * inv,
                                o4[qi].z * inv, o4[qi].w * inv);
        *(float4*)&ob[((size_t)(b * L_ + i0 + r) * H_ + h) * HD_ + cg + 32 * qi] = c4;
    }
}

extern "C" void kernel_launch(void* const* d_in, const int* in_sizes, int n_in,
                              void* d_out, int out_size, void* d_ws, size_t ws_size,
                              hipStream_t stream) {
    const float* x  = (const float*)d_in[0];
    const float* Wq = (const float*)d_in[1];
    const float* Wk = (const float*)d_in[2];
    const float* Wv = (const float*)d_in[3];
    const float* Wo = (const float*)d_in[4];
    float* out = (float*)d_out;

    const int M = B_ * L_;                      // 4096
    char* w = (char*)d_ws;
    float* qbuf  = (float*)w;                                      w += (size_t)M * E_ * 4;        // 33.5 MB
    float* kvbuf = (float*)w;                                      w += (size_t)M * 1024 * 4;      // 16.8 MB
    unsigned short* xb   = (unsigned short*)w;                     w += (size_t)M * E_ * 2;        // 16.8 MB (reused as attn-out bf16)
    unsigned short* wT1  = (unsigned short*)w;                     w += (size_t)E_ * E_ * 2;       // 8.4 MB (WqT then WoT)
    unsigned short* wkvT = (unsigned short*)w;                     w += (size_t)1024 * E_ * 2;     // 4.2 MB

    dim3 blk(256);

    // x -> bf16
    conv_f32_bf16<<<dim3((M * E_ / 4 + 255) / 256), blk, 0, stream>>>(x, xb, M * E_ / 4);
    // weight transposes -> bf16 B^T
    transpose_f32_bf16<<<dim3(E_ / 32, E_ / 32), blk, 0, stream>>>(Wq, wT1, E_, E_, E_);
    transpose_f32_bf16<<<dim3(512 / 32, E_ / 32), blk, 0, stream>>>(Wk, wkvT, E_, 512, E_);
    transpose_f32_bf16<<<dim3(512 / 32, E_ / 32), blk, 0, stream>>>(Wv, wkvT + (size_t)512 * E_, E_, 512, E_);

    // projections (MFMA)
    gemm_bt_bf16<<<dim3(E_ / 128, M / 128), blk, 0, stream>>>(xb, wT1, qbuf, M, E_, E_);
    gemm_bt_bf16<<<dim3(1024 / 128, M / 128), blk, 0, stream>>>(xb, wkvT, kvbuf, M, 1024, E_);

    // windowed attention (fp32), k/v interleaved in kvbuf with row stride 1024
    attn_swa<<<dim3(L_ / QB, B_ * H_), blk, 0, stream>>>(
        qbuf, kvbuf, kvbuf + 512, qbuf, 1024);

    // Wo transpose reuses wT1 (Q-GEMM already consumed it, stream-ordered)
    transpose_f32_bf16<<<dim3(E_ / 32, E_ / 32), blk, 0, stream>>>(Wo, wT1, E_, E_, E_);
    // attention output -> bf16 (reuses xb; projections already consumed it)
    conv_f32_bf16<<<dim3((M * E_ / 4 + 255) / 256), blk, 0, stream>>>(qbuf, xb, M * E_ / 4);
    // output projection (MFMA)
    gemm_bt_bf16<<<dim3(E_ / 128, M / 128), blk, 0, stream>>>(xb, wT1, out, M, E_, E_);
}

// Round 6
// 366.213 us; speedup vs baseline: 5.0999x; 2.4038x over previous
//
#include <hip/hip_runtime.h>
#include <hip/hip_bf16.h>
#include <type_traits>

#define B_ 2
#define L_ 2048
#define E_ 2048
#define H_ 16
#define KVH_ 4
#define HD_ 128
#define WIN_ 512
#define REP_ (H_ / KVH_)
#define SCALE_ 0.08838834764831843f

typedef __bf16 bf16x8 __attribute__((ext_vector_type(8)));
typedef float f32x4 __attribute__((ext_vector_type(4)));
typedef unsigned short u16x8 __attribute__((ext_vector_type(8)));

__device__ __forceinline__ unsigned short f2bf(float x) {
    __hip_bfloat16 h = __float2bfloat16(x);
    return *reinterpret_cast<unsigned short*>(&h);
}

__device__ __forceinline__ void gload_lds16(const unsigned short* g, unsigned short* l) {
    __builtin_amdgcn_global_load_lds(
        (const __attribute__((address_space(1))) void*)g,
        (__attribute__((address_space(3))) void*)l,
        16, 0, 0);
}

// ---------------- fp32 -> bf16 elementwise convert ----------------
__global__ __launch_bounds__(256) void conv_f32_bf16(
        const float* __restrict__ in, unsigned short* __restrict__ out, int n4) {
    int i = blockIdx.x * 256 + threadIdx.x;
    if (i >= n4) return;
    float4 v = reinterpret_cast<const float4*>(in)[i];
    ushort4 o;
    o.x = f2bf(v.x); o.y = f2bf(v.y); o.z = f2bf(v.z); o.w = f2bf(v.w);
    reinterpret_cast<ushort4*>(out)[i] = o;
}

// ---------------- fp32 [K][N] -> bf16 [N][K] transpose ----------------
__global__ __launch_bounds__(256) void transpose_f32_bf16(
        const float* __restrict__ W, unsigned short* __restrict__ WT,
        int K, int N, int wts) {
    __shared__ unsigned short tile[32][33];
    const int t = threadIdx.x;
    const int r = t >> 5, c = t & 31;
    const int k0 = blockIdx.y * 32, n0 = blockIdx.x * 32;
    #pragma unroll
    for (int i = 0; i < 4; ++i)
        tile[r + i * 8][c] = f2bf(W[(size_t)(k0 + r + i * 8) * N + n0 + c]);
    __syncthreads();
    #pragma unroll
    for (int i = 0; i < 4; ++i)
        WT[(size_t)(n0 + r + i * 8) * wts + k0 + c] = tile[c][r + i * 8];
}

// ------- bf16 V-half of kvbuf [B*L][1024] -> vT [(b,kh,dv)=1024][L] -------
__global__ __launch_bounds__(256) void transpose_v_bf16(
        const unsigned short* __restrict__ kv, unsigned short* __restrict__ vT) {
    __shared__ unsigned short tile[32][33];
    const int t = threadIdx.x;
    const int r = t >> 5, c = t & 31;
    const int l0 = blockIdx.y * 32;        // over B*L (4096)
    const int n0 = blockIdx.x * 32;        // over 512 V cols
    #pragma unroll
    for (int i = 0; i < 4; ++i)
        tile[r + i * 8][c] = kv[(size_t)(l0 + r + i * 8) * 1024 + 512 + n0 + c];
    __syncthreads();
    const int bq = l0 >> 11, lqv = l0 & 2047;
    #pragma unroll
    for (int i = 0; i < 4; ++i)
        vT[(size_t)(bq * 512 + n0 + r + i * 8) * (size_t)L_ + lqv + c] = tile[c][r + i * 8];
}

// ---------------- bf16 MFMA GEMM: C = A @ BT^T (m97 structure) --------------
template<typename OT>
__global__ __launch_bounds__(256) void gemm_bt(
        const unsigned short* __restrict__ A, const unsigned short* __restrict__ BT,
        OT* __restrict__ C, int M, int N, int K) {
    __shared__ __attribute__((aligned(16))) unsigned short As[128 * 32];
    __shared__ __attribute__((aligned(16))) unsigned short Bs[128 * 32];
    const int t  = threadIdx.x;
    const int wv = t >> 6, ln = t & 63;
    const int wr = wv >> 1, wc = wv & 1;
    const int bm = blockIdx.y * 128, bn = blockIdx.x * 128;
    const int lrow = ln & 15;
    const int lk8  = (ln >> 4) * 8;

    f32x4 acc[4][4];
    const f32x4 z = {0.f, 0.f, 0.f, 0.f};
    #pragma unroll
    for (int m = 0; m < 4; ++m)
        #pragma unroll
        for (int n = 0; n < 4; ++n) acc[m][n] = z;

    for (int k0 = 0; k0 < K; k0 += 32) {
        #pragma unroll
        for (int seg = 0; seg < 2; ++seg) {
            const int chunk = seg * 256 + t;
            const int row = chunk >> 2, c8 = (chunk & 3) * 8;
            const int lbase = (seg * 256 + wv * 64) * 8;
            gload_lds16(A  + (size_t)(bm + row) * K + k0 + c8, &As[lbase]);
            gload_lds16(BT + (size_t)(bn + row) * K + k0 + c8, &Bs[lbase]);
        }
        __syncthreads();
        bf16x8 af[4], bfr[4];
        #pragma unroll
        for (int m = 0; m < 4; ++m)
            af[m] = *reinterpret_cast<const bf16x8*>(
                &As[(wr * 64 + m * 16 + lrow) * 32 + lk8]);
        #pragma unroll
        for (int n = 0; n < 4; ++n)
            bfr[n] = *reinterpret_cast<const bf16x8*>(
                &Bs[(wc * 64 + n * 16 + lrow) * 32 + lk8]);
        #pragma unroll
        for (int m = 0; m < 4; ++m)
            #pragma unroll
            for (int n = 0; n < 4; ++n)
                acc[m][n] = __builtin_amdgcn_mfma_f32_16x16x32_bf16(
                    af[m], bfr[n], acc[m][n], 0, 0, 0);
        __syncthreads();
    }
    const int crq = (ln >> 4) * 4;
    #pragma unroll
    for (int m = 0; m < 4; ++m)
        #pragma unroll
        for (int n = 0; n < 4; ++n)
            #pragma unroll
            for (int r = 0; r < 4; ++r) {
                size_t idx = (size_t)(bm + wr * 64 + m * 16 + crq + r) * N
                             + bn + wc * 64 + n * 16 + lrow;
                if constexpr (std::is_same_v<OT, float>) C[idx] = acc[m][n][r];
                else C[idx] = f2bf(acc[m][n][r]);
            }
}

// ---------------- bf16 MFMA windowed flash attention (no tr-read) -----------
// qb: [B*L][E] bf16; kvb: [B*L][1024] (K at kh*128); vT: [(b*4+kh)*128+dv][L].
// Block: 64 q-rows x (b,h); 4 waves x 16 q-rows. PV via O^T = mfma(V^T, P^T).
__global__ __launch_bounds__(256) void attn_mfma(
        const unsigned short* __restrict__ qb,
        const unsigned short* __restrict__ kvb,
        const unsigned short* __restrict__ vT,
        unsigned short* __restrict__ ob) {
    __shared__ __attribute__((aligned(16))) unsigned short Ks[32 * 128];
    __shared__ __attribute__((aligned(16))) unsigned short VsT[128 * 40];
    __shared__ __bf16 Pl[4][32][17];

    const int t  = threadIdx.x;
    const int w  = t >> 6, l = t & 63;
    const int bh = blockIdx.y;
    const int b  = bh >> 4, h = bh & 15;
    const int kh = h >> 2;
    const int i0 = blockIdx.x * 64;
    const int iw = i0 + w * 16;          // wave's q base
    const int lq = l & 15;               // lane's q index (own query)
    const int g  = l >> 4;               // quad
    const int g8 = g * 8;
    const int i  = iw + lq;

    // Q fragments: lane holds Q[q=lq][d = dc*32 + g8 .. +8]
    bf16x8 qf[4];
    {
        const unsigned short* qrow = qb + (size_t)(b * L_ + iw + lq) * E_ + h * HD_;
        #pragma unroll
        for (int dc = 0; dc < 4; ++dc)
            qf[dc] = *reinterpret_cast<const bf16x8*>(qrow + dc * 32 + g8);
    }

    f32x4 oacc[8];
    const f32x4 z = {0.f, 0.f, 0.f, 0.f};
    #pragma unroll
    for (int c = 0; c < 8; ++c) oacc[c] = z;
    float mreg = -50000.f, lreg = 0.f;

    int jlo = i0 - WIN_; if (jlo < 0) jlo = 0;
    const int nch = (i0 + 64 - jlo) >> 5;
    const int wlo = iw - WIN_, whi = iw + 15;
    const unsigned short* vbase = vT + (size_t)((b * KVH_ + kh) * HD_) * L_;

    for (int ch = 0; ch < nch; ++ch) {
        const int jb = jlo + ch * 32;
        // ---- stage K (XOR-swizzled rows) and V^T (row-major, pitch 40) ----
        #pragma unroll
        for (int s = 0; s < 2; ++s) {
            const int e  = t + s * 256;       // 0..511
            const int kr = e >> 4;            // key row 0..31
            const int d8 = (e & 15) * 8;      // d offset
            u16x8 kk = *reinterpret_cast<const u16x8*>(
                kvb + (size_t)(b * L_ + jb + kr) * 1024 + kh * HD_ + d8);
            *reinterpret_cast<u16x8*>(&Ks[kr * 128 + (d8 ^ ((kr & 7) << 3))]) = kk;
            const int dv = e >> 2;            // 0..127
            const int k8 = (e & 3) * 8;       // key offset 0/8/16/24
            u16x8 vv = *reinterpret_cast<const u16x8*>(
                vbase + (size_t)dv * L_ + jb + k8);
            *reinterpret_cast<u16x8*>(&VsT[dv * 40 + k8]) = vv;
        }
        __syncthreads();

        if (jb + 31 >= wlo && jb <= whi) {
            // ---- swapped QK^T: S^T tile kt, D: row=key=g*4+r, col=q=lq ----
            f32x4 st[2]; st[0] = z; st[1] = z;
            #pragma unroll
            for (int kt = 0; kt < 2; ++kt) {
                const int krow = kt * 16 + lq;
                #pragma unroll
                for (int dc = 0; dc < 4; ++dc) {
                    bf16x8 kf = *reinterpret_cast<const bf16x8*>(
                        &Ks[krow * 128 + ((dc * 32 + g8) ^ ((krow & 7) << 3))]);
                    st[kt] = __builtin_amdgcn_mfma_f32_16x16x32_bf16(
                        kf, qf[dc], st[kt], 0, 0, 0);
                }
            }
            // ---- mask + online softmax (lane's 8 scores all for q = lq) ----
            float p8[2][4];
            float cmax = -1e30f;
            #pragma unroll
            for (int kt = 0; kt < 2; ++kt)
                #pragma unroll
                for (int r = 0; r < 4; ++r) {
                    const int j = jb + kt * 16 + g * 4 + r;
                    float s = st[kt][r] * SCALE_;
                    s = (j <= i && j >= i - WIN_) ? s : -1e30f;
                    p8[kt][r] = s;
                    cmax = fmaxf(cmax, s);
                }
            cmax = fmaxf(cmax, __shfl_xor(cmax, 16));
            cmax = fmaxf(cmax, __shfl_xor(cmax, 32));
            const float mnew  = fmaxf(mreg, cmax);
            const float alpha = __expf(mreg - mnew);
            float psum = 0.f;
            #pragma unroll
            for (int kt = 0; kt < 2; ++kt)
                #pragma unroll
                for (int r = 0; r < 4; ++r) {
                    const float p = __expf(p8[kt][r] - mnew);
                    p8[kt][r] = p; psum += p;
                }
            psum += __shfl_xor(psum, 16);
            psum += __shfl_xor(psum, 32);
            lreg = lreg * alpha + psum;
            mreg = mnew;
            // ---- P^T -> per-wave LDS [k][q] (same-wave round-trip) ----
            #pragma unroll
            for (int kt = 0; kt < 2; ++kt)
                #pragma unroll
                for (int r = 0; r < 4; ++r)
                    Pl[w][kt * 16 + g * 4 + r][lq] = (__bf16)p8[kt][r];
            bf16x8 pb;
            #pragma unroll
            for (int j = 0; j < 8; ++j) pb[j] = Pl[w][g8 + j][lq];
            // ---- rescale O (all oacc belong to own query lq) ----
            #pragma unroll
            for (int c = 0; c < 8; ++c)
                #pragma unroll
                for (int r = 0; r < 4; ++r) oacc[c][r] *= alpha;
            // ---- PV: O^T = mfma(A = V^T-frag, B = P^T-frag) ----
            #pragma unroll
            for (int c = 0; c < 8; ++c) {
                bf16x8 af = *reinterpret_cast<const bf16x8*>(
                    &VsT[(c * 16 + lq) * 40 + g8]);
                oacc[c] = __builtin_amdgcn_mfma_f32_16x16x32_bf16(
                    af, pb, oacc[c], 0, 0, 0);
            }
        }
        __syncthreads();
    }

    // ---- finalize: O[q=iw+lq][dv=c*16+g*4+r] /= l, store bf16 ----
    const float inv = 1.f / lreg;
    unsigned short* orow = ob + (size_t)(b * L_ + iw + lq) * E_ + h * HD_;
    #pragma unroll
    for (int c = 0; c < 8; ++c) {
        ushort4 o4;
        o4.x = f2bf(oacc[c][0] * inv);
        o4.y = f2bf(oacc[c][1] * inv);
        o4.z = f2bf(oacc[c][2] * inv);
        o4.w = f2bf(oacc[c][3] * inv);
        *reinterpret_cast<ushort4*>(&orow[c * 16 + g * 4]) = o4;
    }
}

extern "C" void kernel_launch(void* const* d_in, const int* in_sizes, int n_in,
                              void* d_out, int out_size, void* d_ws, size_t ws_size,
                              hipStream_t stream) {
    const float* x  = (const float*)d_in[0];
    const float* Wq = (const float*)d_in[1];
    const float* Wk = (const float*)d_in[2];
    const float* Wv = (const float*)d_in[3];
    const float* Wo = (const float*)d_in[4];
    float* out = (float*)d_out;

    const int M = B_ * L_;                      // 4096
    char* w = (char*)d_ws;
    unsigned short* qbuf  = (unsigned short*)w; w += (size_t)M * E_ * 2;     // 16.8 MB
    unsigned short* kvbuf = (unsigned short*)w; w += (size_t)M * 1024 * 2;   // 8.4 MB
    unsigned short* xb    = (unsigned short*)w; w += (size_t)M * E_ * 2;     // 16.8 MB (x bf16, then attn out)
    unsigned short* wT1   = (unsigned short*)w; w += (size_t)E_ * E_ * 2;    // 8.4 MB (WqT then WoT)
    unsigned short* wkvT  = (unsigned short*)w; w += (size_t)1024 * E_ * 2;  // 4.2 MB
    unsigned short* vTb   = (unsigned short*)w; w += (size_t)1024 * L_ * 2;  // 4.2 MB

    dim3 blk(256);

    conv_f32_bf16<<<dim3((M * E_ / 4 + 255) / 256), blk, 0, stream>>>(x, xb, M * E_ / 4);
    transpose_f32_bf16<<<dim3(E_ / 32, E_ / 32), blk, 0, stream>>>(Wq, wT1, E_, E_, E_);
    transpose_f32_bf16<<<dim3(512 / 32, E_ / 32), blk, 0, stream>>>(Wk, wkvT, E_, 512, E_);
    transpose_f32_bf16<<<dim3(512 / 32, E_ / 32), blk, 0, stream>>>(Wv, wkvT + (size_t)512 * E_, E_, 512, E_);

    gemm_bt<unsigned short><<<dim3(E_ / 128, M / 128), blk, 0, stream>>>(
        xb, wT1, qbuf, M, E_, E_);
    gemm_bt<unsigned short><<<dim3(1024 / 128, M / 128), blk, 0, stream>>>(
        xb, wkvT, kvbuf, M, 1024, E_);

    // V-half of kvbuf -> vT [(b*4+kh)*128+dv][L]
    transpose_v_bf16<<<dim3(512 / 32, M / 32), blk, 0, stream>>>(kvbuf, vTb);

    // attention writes bf16 directly into xb (its x-content is already consumed)
    attn_mfma<<<dim3(L_ / 64, B_ * H_), blk, 0, stream>>>(qbuf, kvbuf, vTb, xb);

    transpose_f32_bf16<<<dim3(E_ / 32, E_ / 32), blk, 0, stream>>>(Wo, wT1, E_, E_, E_);
    gemm_bt<float><<<dim3(E_ / 128, M / 128), blk, 0, stream>>>(xb, wT1, out, M, E_, E_);
}

// Round 7
// 344.532 us; speedup vs baseline: 5.4209x; 1.0629x over previous
//
#include <hip/hip_runtime.h>
#include <hip/hip_bf16.h>
#include <type_traits>

#define B_ 2
#define L_ 2048
#define E_ 2048
#define H_ 16
#define KVH_ 4
#define HD_ 128
#define WIN_ 512
#define REP_ (H_ / KVH_)
#define SCALE_ 0.08838834764831843f

typedef __bf16 bf16x8 __attribute__((ext_vector_type(8)));
typedef float f32x4 __attribute__((ext_vector_type(4)));
typedef unsigned short u16x8 __attribute__((ext_vector_type(8)));

__device__ __forceinline__ unsigned short f2bf(float x) {
    __hip_bfloat16 h = __float2bfloat16(x);
    return *reinterpret_cast<unsigned short*>(&h);
}

__device__ __forceinline__ void gload_lds16(const unsigned short* g, unsigned short* l) {
    __builtin_amdgcn_global_load_lds(
        (const __attribute__((address_space(1))) void*)g,
        (__attribute__((address_space(3))) void*)l,
        16, 0, 0);
}

// ---------------- fp32 -> bf16 elementwise convert ----------------
__global__ __launch_bounds__(256) void conv_f32_bf16(
        const float* __restrict__ in, unsigned short* __restrict__ out, int n4) {
    int i = blockIdx.x * 256 + threadIdx.x;
    if (i >= n4) return;
    float4 v = reinterpret_cast<const float4*>(in)[i];
    ushort4 o;
    o.x = f2bf(v.x); o.y = f2bf(v.y); o.z = f2bf(v.z); o.w = f2bf(v.w);
    reinterpret_cast<ushort4*>(out)[i] = o;
}

// ---------------- fp32 [K][N] -> bf16 [N][K] transpose ----------------
__global__ __launch_bounds__(256) void transpose_f32_bf16(
        const float* __restrict__ W, unsigned short* __restrict__ WT,
        int K, int N, int wts) {
    __shared__ unsigned short tile[32][33];
    const int t = threadIdx.x;
    const int r = t >> 5, c = t & 31;
    const int k0 = blockIdx.y * 32, n0 = blockIdx.x * 32;
    #pragma unroll
    for (int i = 0; i < 4; ++i)
        tile[r + i * 8][c] = f2bf(W[(size_t)(k0 + r + i * 8) * N + n0 + c]);
    __syncthreads();
    #pragma unroll
    for (int i = 0; i < 4; ++i)
        WT[(size_t)(n0 + r + i * 8) * wts + k0 + c] = tile[c][r + i * 8];
}

// ------- bf16 V-half of kvbuf [B*L][1024] -> vT [(b,kh,dv)=1024][L] -------
__global__ __launch_bounds__(256) void transpose_v_bf16(
        const unsigned short* __restrict__ kv, unsigned short* __restrict__ vT) {
    __shared__ unsigned short tile[32][33];
    const int t = threadIdx.x;
    const int r = t >> 5, c = t & 31;
    const int l0 = blockIdx.y * 32;        // over B*L (4096)
    const int n0 = blockIdx.x * 32;        // over 512 V cols
    #pragma unroll
    for (int i = 0; i < 4; ++i)
        tile[r + i * 8][c] = kv[(size_t)(l0 + r + i * 8) * 1024 + 512 + n0 + c];
    __syncthreads();
    const int bq = l0 >> 11, lqv = l0 & 2047;
    #pragma unroll
    for (int i = 0; i < 4; ++i)
        vT[(size_t)(bq * 512 + n0 + r + i * 8) * (size_t)L_ + lqv + c] = tile[c][r + i * 8];
}

// ---------------- bf16 MFMA GEMM: C = A @ BT^T (m97 structure) --------------
template<typename OT>
__global__ __launch_bounds__(256) void gemm_bt(
        const unsigned short* __restrict__ A, const unsigned short* __restrict__ BT,
        OT* __restrict__ C, int M, int N, int K) {
    __shared__ __attribute__((aligned(16))) unsigned short As[128 * 32];
    __shared__ __attribute__((aligned(16))) unsigned short Bs[128 * 32];
    const int t  = threadIdx.x;
    const int wv = t >> 6, ln = t & 63;
    const int wr = wv >> 1, wc = wv & 1;
    // XCD-chunked bijective swizzle (nwg % 8 == 0 for all our grids)
    const int nwg = gridDim.x * gridDim.y;
    int lin = blockIdx.y * gridDim.x + blockIdx.x;
    if ((nwg & 7) == 0) lin = (lin & 7) * (nwg >> 3) + (lin >> 3);
    const int bm = (lin / gridDim.x) * 128, bn = (lin % gridDim.x) * 128;
    const int lrow = ln & 15;
    const int lk8  = (ln >> 4) * 8;

    f32x4 acc[4][4];
    const f32x4 z = {0.f, 0.f, 0.f, 0.f};
    #pragma unroll
    for (int m = 0; m < 4; ++m)
        #pragma unroll
        for (int n = 0; n < 4; ++n) acc[m][n] = z;

    for (int k0 = 0; k0 < K; k0 += 32) {
        #pragma unroll
        for (int seg = 0; seg < 2; ++seg) {
            const int chunk = seg * 256 + t;
            const int row = chunk >> 2, c8 = (chunk & 3) * 8;
            const int lbase = (seg * 256 + wv * 64) * 8;
            gload_lds16(A  + (size_t)(bm + row) * K + k0 + c8, &As[lbase]);
            gload_lds16(BT + (size_t)(bn + row) * K + k0 + c8, &Bs[lbase]);
        }
        __syncthreads();
        bf16x8 af[4], bfr[4];
        #pragma unroll
        for (int m = 0; m < 4; ++m)
            af[m] = *reinterpret_cast<const bf16x8*>(
                &As[(wr * 64 + m * 16 + lrow) * 32 + lk8]);
        #pragma unroll
        for (int n = 0; n < 4; ++n)
            bfr[n] = *reinterpret_cast<const bf16x8*>(
                &Bs[(wc * 64 + n * 16 + lrow) * 32 + lk8]);
        __builtin_amdgcn_s_setprio(1);
        #pragma unroll
        for (int m = 0; m < 4; ++m)
            #pragma unroll
            for (int n = 0; n < 4; ++n)
                acc[m][n] = __builtin_amdgcn_mfma_f32_16x16x32_bf16(
                    af[m], bfr[n], acc[m][n], 0, 0, 0);
        __builtin_amdgcn_s_setprio(0);
        __syncthreads();
    }
    const int crq = (ln >> 4) * 4;
    #pragma unroll
    for (int m = 0; m < 4; ++m)
        #pragma unroll
        for (int n = 0; n < 4; ++n)
            #pragma unroll
            for (int r = 0; r < 4; ++r) {
                size_t idx = (size_t)(bm + wr * 64 + m * 16 + crq + r) * N
                             + bn + wc * 64 + n * 16 + lrow;
                if constexpr (std::is_same_v<OT, float>) C[idx] = acc[m][n][r];
                else C[idx] = f2bf(acc[m][n][r]);
            }
}

// ---------------- bf16 MFMA windowed flash attention -----------------------
// qb: [B*L][E] bf16; kvb: [B*L][1024] (K at kh*128); vT: [(b*4+kh)*128+dv][L].
// Block: 64 q-rows x (b,h); 4 waves x 16 q-rows. PV via O^T = mfma(V^T, P^T).
__global__ __launch_bounds__(256) void attn_mfma(
        const unsigned short* __restrict__ qb,
        const unsigned short* __restrict__ kvb,
        const unsigned short* __restrict__ vT,
        unsigned short* __restrict__ ob) {
    __shared__ __attribute__((aligned(16))) unsigned short Ks[32 * 128];
    __shared__ __attribute__((aligned(16))) unsigned short VsT[128 * 40];

    const int t  = threadIdx.x;
    const int w  = t >> 6, l = t & 63;
    // work remap: each XCD owns one (b,kh) KV slab; long q-tiles dispatched first
    const int lin = blockIdx.y * gridDim.x + blockIdx.x;   // 0..1023
    const int wid = (lin & 7) * 128 + (lin >> 3);
    const int bh  = wid >> 5;
    const int qt  = 31 - (wid & 31);
    const int b  = bh >> 4, h = bh & 15;
    const int kh = h >> 2;
    const int i0 = qt * 64;
    const int iw = i0 + w * 16;          // wave's q base
    const int lq = l & 15;               // lane's q index (own query)
    const int g  = l >> 4;               // quad
    const int g8 = g * 8;
    const int i  = iw + lq;

    // Q fragments: lane holds Q[q=lq][d = dc*32 + g8 .. +8]
    bf16x8 qf[4];
    {
        const unsigned short* qrow = qb + (size_t)(b * L_ + iw + lq) * E_ + h * HD_;
        #pragma unroll
        for (int dc = 0; dc < 4; ++dc)
            qf[dc] = *reinterpret_cast<const bf16x8*>(qrow + dc * 32 + g8);
    }

    f32x4 oacc[8];
    const f32x4 z = {0.f, 0.f, 0.f, 0.f};
    #pragma unroll
    for (int c = 0; c < 8; ++c) oacc[c] = z;
    float mreg = -50000.f, lreg = 0.f;

    int jlo = i0 - WIN_; if (jlo < 0) jlo = 0;
    const int nch = (i0 + 64 - jlo) >> 5;
    const int wlo = iw - WIN_, whi = iw + 15;
    const unsigned short* vbase = vT + (size_t)((b * KVH_ + kh) * HD_) * L_;

    for (int ch = 0; ch < nch; ++ch) {
        const int jb = jlo + ch * 32;
        // ---- stage K (XOR-swizzled rows) and V^T (row-major, pitch 40) ----
        #pragma unroll
        for (int s = 0; s < 2; ++s) {
            const int e  = t + s * 256;       // 0..511
            const int kr = e >> 4;            // key row 0..31
            const int d8 = (e & 15) * 8;      // d offset
            u16x8 kk = *reinterpret_cast<const u16x8*>(
                kvb + (size_t)(b * L_ + jb + kr) * 1024 + kh * HD_ + d8);
            *reinterpret_cast<u16x8*>(&Ks[kr * 128 + (d8 ^ ((kr & 7) << 3))]) = kk;
            const int dv = e >> 2;            // 0..127
            const int k8 = (e & 3) * 8;       // key offset 0/8/16/24
            u16x8 vv = *reinterpret_cast<const u16x8*>(
                vbase + (size_t)dv * L_ + jb + k8);
            *reinterpret_cast<u16x8*>(&VsT[dv * 40 + k8]) = vv;
        }
        __syncthreads();

        if (jb + 31 >= wlo && jb <= whi) {
            // ---- swapped QK^T: S^T tile kt, D: row=key=g*4+r, col=q=lq ----
            f32x4 st[2]; st[0] = z; st[1] = z;
            __builtin_amdgcn_s_setprio(1);
            #pragma unroll
            for (int kt = 0; kt < 2; ++kt) {
                const int krow = kt * 16 + lq;
                #pragma unroll
                for (int dc = 0; dc < 4; ++dc) {
                    bf16x8 kf = *reinterpret_cast<const bf16x8*>(
                        &Ks[krow * 128 + ((dc * 32 + g8) ^ ((krow & 7) << 3))]);
                    st[kt] = __builtin_amdgcn_mfma_f32_16x16x32_bf16(
                        kf, qf[dc], st[kt], 0, 0, 0);
                }
            }
            __builtin_amdgcn_s_setprio(0);
            // ---- mask + online softmax (lane's 8 scores all for q = lq) ----
            float p8[2][4];
            float cmax = -1e30f;
            #pragma unroll
            for (int kt = 0; kt < 2; ++kt)
                #pragma unroll
                for (int r = 0; r < 4; ++r) {
                    const int j = jb + kt * 16 + g * 4 + r;
                    float s = st[kt][r] * SCALE_;
                    s = (j <= i && j >= i - WIN_) ? s : -1e30f;
                    p8[kt][r] = s;
                    cmax = fmaxf(cmax, s);
                }
            cmax = fmaxf(cmax, __shfl_xor(cmax, 16));
            cmax = fmaxf(cmax, __shfl_xor(cmax, 32));
            // T13 defer-rescale: skip alpha-pass unless max grew by > 8
            const bool noresc = __all(cmax - mreg <= 8.f);
            float alpha = 1.f;
            if (!noresc) {
                const float mnew = fmaxf(mreg, cmax);
                alpha = __expf(mreg - mnew);
                mreg = mnew;
            }
            float psum = 0.f;
            #pragma unroll
            for (int kt = 0; kt < 2; ++kt)
                #pragma unroll
                for (int r = 0; r < 4; ++r) {
                    const float p = __expf(p8[kt][r] - mreg);
                    p8[kt][r] = p; psum += p;
                }
            psum += __shfl_xor(psum, 16);
            psum += __shfl_xor(psum, 32);
            if (noresc) {
                lreg += psum;
            } else {
                lreg = lreg * alpha + psum;
                #pragma unroll
                for (int c = 0; c < 8; ++c)
                    #pragma unroll
                    for (int r = 0; r < 4; ++r) oacc[c][r] *= alpha;
            }
            // ---- P^T B-fragment via cross-lane shuffles (no LDS) ----
            // src side: pack bf16 pairs per kt/r-pair
            const unsigned u00 = ((unsigned)f2bf(p8[0][1]) << 16) | f2bf(p8[0][0]);
            const unsigned u01 = ((unsigned)f2bf(p8[0][3]) << 16) | f2bf(p8[0][2]);
            const unsigned u10 = ((unsigned)f2bf(p8[1][1]) << 16) | f2bf(p8[1][0]);
            const unsigned u11 = ((unsigned)f2bf(p8[1][3]) << 16) | f2bf(p8[1][2]);
            // dest word wd holds P[q=lq][k=8g+2wd, 8g+2wd+1]:
            //   src lane = ((g&1)*2 + (wd>>1))*16 + lq, var kt = g>>1
            union { unsigned u[4]; bf16x8 v; } pu;
            #pragma unroll
            for (int wd = 0; wd < 4; ++wd) {
                const int src = ((g & 1) * 2 + (wd >> 1)) * 16 + lq;
                const unsigned a0 = __shfl(wd & 1 ? u01 : u00, src);
                const unsigned a1 = __shfl(wd & 1 ? u11 : u10, src);
                pu.u[wd] = (g < 2) ? a0 : a1;
            }
            const bf16x8 pb = pu.v;
            // ---- PV: O^T = mfma(A = V^T-frag, B = P^T-frag) ----
            __builtin_amdgcn_s_setprio(1);
            #pragma unroll
            for (int c = 0; c < 8; ++c) {
                bf16x8 af = *reinterpret_cast<const bf16x8*>(
                    &VsT[(c * 16 + lq) * 40 + g8]);
                oacc[c] = __builtin_amdgcn_mfma_f32_16x16x32_bf16(
                    af, pb, oacc[c], 0, 0, 0);
            }
            __builtin_amdgcn_s_setprio(0);
        }
        __syncthreads();
    }

    // ---- finalize: O[q=iw+lq][dv=c*16+g*4+r] /= l, store bf16 ----
    const float inv = 1.f / lreg;
    unsigned short* orow = ob + (size_t)(b * L_ + iw + lq) * E_ + h * HD_;
    #pragma unroll
    for (int c = 0; c < 8; ++c) {
        ushort4 o4;
        o4.x = f2bf(oacc[c][0] * inv);
        o4.y = f2bf(oacc[c][1] * inv);
        o4.z = f2bf(oacc[c][2] * inv);
        o4.w = f2bf(oacc[c][3] * inv);
        *reinterpret_cast<ushort4*>(&orow[c * 16 + g * 4]) = o4;
    }
}

extern "C" void kernel_launch(void* const* d_in, const int* in_sizes, int n_in,
                              void* d_out, int out_size, void* d_ws, size_t ws_size,
                              hipStream_t stream) {
    const float* x  = (const float*)d_in[0];
    const float* Wq = (const float*)d_in[1];
    const float* Wk = (const float*)d_in[2];
    const float* Wv = (const float*)d_in[3];
    const float* Wo = (const float*)d_in[4];
    float* out = (float*)d_out;

    const int M = B_ * L_;                      // 4096
    char* w = (char*)d_ws;
    unsigned short* qbuf  = (unsigned short*)w; w += (size_t)M * E_ * 2;     // 16.8 MB
    unsigned short* kvbuf = (unsigned short*)w; w += (size_t)M * 1024 * 2;   // 8.4 MB
    unsigned short* xb    = (unsigned short*)w; w += (size_t)M * E_ * 2;     // 16.8 MB (x bf16, then attn out)
    unsigned short* wT1   = (unsigned short*)w; w += (size_t)E_ * E_ * 2;    // 8.4 MB (WqT then WoT)
    unsigned short* wkvT  = (unsigned short*)w; w += (size_t)1024 * E_ * 2;  // 4.2 MB
    unsigned short* vTb   = (unsigned short*)w; w += (size_t)1024 * L_ * 2;  // 4.2 MB

    dim3 blk(256);

    conv_f32_bf16<<<dim3((M * E_ / 4 + 255) / 256), blk, 0, stream>>>(x, xb, M * E_ / 4);
    transpose_f32_bf16<<<dim3(E_ / 32, E_ / 32), blk, 0, stream>>>(Wq, wT1, E_, E_, E_);
    transpose_f32_bf16<<<dim3(512 / 32, E_ / 32), blk, 0, stream>>>(Wk, wkvT, E_, 512, E_);
    transpose_f32_bf16<<<dim3(512 / 32, E_ / 32), blk, 0, stream>>>(Wv, wkvT + (size_t)512 * E_, E_, 512, E_);

    gemm_bt<unsigned short><<<dim3(E_ / 128, M / 128), blk, 0, stream>>>(
        xb, wT1, qbuf, M, E_, E_);
    gemm_bt<unsigned short><<<dim3(1024 / 128, M / 128), blk, 0, stream>>>(
        xb, wkvT, kvbuf, M, 1024, E_);

    // V-half of kvbuf -> vT [(b*4+kh)*128+dv][L]
    transpose_v_bf16<<<dim3(512 / 32, M / 32), blk, 0, stream>>>(kvbuf, vTb);

    // attention writes bf16 directly into xb (its x-content is already consumed)
    attn_mfma<<<dim3(L_ / 64, B_ * H_), blk, 0, stream>>>(qbuf, kvbuf, vTb, xb);

    transpose_f32_bf16<<<dim3(E_ / 32, E_ / 32), blk, 0, stream>>>(Wo, wT1, E_, E_, E_);
    gemm_bt<float><<<dim3(E_ / 128, M / 128), blk, 0, stream>>>(xb, wT1, out, M, E_, E_);
}

// Round 8
// 303.358 us; speedup vs baseline: 6.1566x; 1.1357x over previous
//
#include <hip/hip_runtime.h>
#include <hip/hip_bf16.h>
#include <type_traits>

#define B_ 2
#define L_ 2048
#define E_ 2048
#define H_ 16
#define KVH_ 4
#define HD_ 128
#define WIN_ 512
#define REP_ (H_ / KVH_)
#define SCALE_ 0.08838834764831843f
#define QKVP_ 3072   // fused qkv row pitch

typedef __bf16 bf16x8 __attribute__((ext_vector_type(8)));
typedef float f32x4 __attribute__((ext_vector_type(4)));
typedef unsigned short u16x8 __attribute__((ext_vector_type(8)));

__device__ __forceinline__ unsigned short f2bf(float x) {
    __hip_bfloat16 h = __float2bfloat16(x);
    return *reinterpret_cast<unsigned short*>(&h);
}

__device__ __forceinline__ void gload_lds16(const unsigned short* g, unsigned short* l) {
    __builtin_amdgcn_global_load_lds(
        (const __attribute__((address_space(1))) void*)g,
        (__attribute__((address_space(3))) void*)l,
        16, 0, 0);
}

// ---------------- fp32 -> bf16 elementwise convert ----------------
__global__ __launch_bounds__(256) void conv_f32_bf16(
        const float* __restrict__ in, unsigned short* __restrict__ out, int n4) {
    int i = blockIdx.x * 256 + threadIdx.x;
    if (i >= n4) return;
    float4 v = reinterpret_cast<const float4*>(in)[i];
    ushort4 o;
    o.x = f2bf(v.x); o.y = f2bf(v.y); o.z = f2bf(v.z); o.w = f2bf(v.w);
    reinterpret_cast<ushort4*>(out)[i] = o;
}

// ---------------- fp32 [K][N] -> bf16 [N][K] transpose ----------------
__global__ __launch_bounds__(256) void transpose_f32_bf16(
        const float* __restrict__ W, unsigned short* __restrict__ WT,
        int K, int N, int wts) {
    __shared__ unsigned short tile[32][33];
    const int t = threadIdx.x;
    const int r = t >> 5, c = t & 31;
    const int k0 = blockIdx.y * 32, n0 = blockIdx.x * 32;
    #pragma unroll
    for (int i = 0; i < 4; ++i)
        tile[r + i * 8][c] = f2bf(W[(size_t)(k0 + r + i * 8) * N + n0 + c]);
    __syncthreads();
    #pragma unroll
    for (int i = 0; i < 4; ++i)
        WT[(size_t)(n0 + r + i * 8) * wts + k0 + c] = tile[c][r + i * 8];
}

// ------- fused Wq|Wk|Wv -> bf16 WT [3072][2048] -------
__global__ __launch_bounds__(256) void transpose_wqkv(
        const float* __restrict__ Wq, const float* __restrict__ Wk,
        const float* __restrict__ Wv, unsigned short* __restrict__ WT) {
    __shared__ unsigned short tile[32][33];
    const int t = threadIdx.x;
    const int r = t >> 5, c = t & 31;
    const int n0 = blockIdx.x * 32, k0 = blockIdx.y * 32;
    const float* src; int scol, sN;
    if (n0 < 2048)      { src = Wq; scol = n0;        sN = 2048; }
    else if (n0 < 2560) { src = Wk; scol = n0 - 2048; sN = 512;  }
    else                { src = Wv; scol = n0 - 2560; sN = 512;  }
    #pragma unroll
    for (int i = 0; i < 4; ++i)
        tile[r + i * 8][c] = f2bf(src[(size_t)(k0 + r + i * 8) * sN + scol + c]);
    __syncthreads();
    #pragma unroll
    for (int i = 0; i < 4; ++i)
        WT[(size_t)(n0 + r + i * 8) * 2048 + k0 + c] = tile[c][r + i * 8];
}

// ------- V cols of qkv [B*L][3072] -> vT [(b*4+kh)*128+dv][L] -------
__global__ __launch_bounds__(256) void transpose_v_bf16(
        const unsigned short* __restrict__ qkv, unsigned short* __restrict__ vT) {
    __shared__ unsigned short tile[32][33];
    const int t = threadIdx.x;
    const int r = t >> 5, c = t & 31;
    const int l0 = blockIdx.y * 32;        // over B*L (4096)
    const int n0 = blockIdx.x * 32;        // over 512 V cols
    #pragma unroll
    for (int i = 0; i < 4; ++i)
        tile[r + i * 8][c] = qkv[(size_t)(l0 + r + i * 8) * QKVP_ + 2560 + n0 + c];
    __syncthreads();
    const int bq = l0 >> 11, lqv = l0 & 2047;
    #pragma unroll
    for (int i = 0; i < 4; ++i)
        vT[(size_t)(bq * 512 + n0 + r + i * 8) * (size_t)L_ + lqv + c] = tile[c][r + i * 8];
}

// ---------------- bf16 MFMA GEMM: C = A @ BT^T (m97 structure) --------------
template<typename OT>
__global__ __launch_bounds__(256) void gemm_bt(
        const unsigned short* __restrict__ A, const unsigned short* __restrict__ BT,
        OT* __restrict__ C, int M, int N, int K) {
    __shared__ __attribute__((aligned(16))) unsigned short As[128 * 32];
    __shared__ __attribute__((aligned(16))) unsigned short Bs[128 * 32];
    const int t  = threadIdx.x;
    const int wv = t >> 6, ln = t & 63;
    const int wr = wv >> 1, wc = wv & 1;
    const int nwg = gridDim.x * gridDim.y;
    int lin = blockIdx.y * gridDim.x + blockIdx.x;
    if ((nwg & 7) == 0) lin = (lin & 7) * (nwg >> 3) + (lin >> 3);
    const int bm = (lin / gridDim.x) * 128, bn = (lin % gridDim.x) * 128;
    const int lrow = ln & 15;
    const int lk8  = (ln >> 4) * 8;

    f32x4 acc[4][4];
    const f32x4 z = {0.f, 0.f, 0.f, 0.f};
    #pragma unroll
    for (int m = 0; m < 4; ++m)
        #pragma unroll
        for (int n = 0; n < 4; ++n) acc[m][n] = z;

    for (int k0 = 0; k0 < K; k0 += 32) {
        #pragma unroll
        for (int seg = 0; seg < 2; ++seg) {
            const int chunk = seg * 256 + t;
            const int row = chunk >> 2, c8 = (chunk & 3) * 8;
            const int lbase = (seg * 256 + wv * 64) * 8;
            gload_lds16(A  + (size_t)(bm + row) * K + k0 + c8, &As[lbase]);
            gload_lds16(BT + (size_t)(bn + row) * K + k0 + c8, &Bs[lbase]);
        }
        __syncthreads();
        bf16x8 af[4], bfr[4];
        #pragma unroll
        for (int m = 0; m < 4; ++m)
            af[m] = *reinterpret_cast<const bf16x8*>(
                &As[(wr * 64 + m * 16 + lrow) * 32 + lk8]);
        #pragma unroll
        for (int n = 0; n < 4; ++n)
            bfr[n] = *reinterpret_cast<const bf16x8*>(
                &Bs[(wc * 64 + n * 16 + lrow) * 32 + lk8]);
        __builtin_amdgcn_s_setprio(1);
        #pragma unroll
        for (int m = 0; m < 4; ++m)
            #pragma unroll
            for (int n = 0; n < 4; ++n)
                acc[m][n] = __builtin_amdgcn_mfma_f32_16x16x32_bf16(
                    af[m], bfr[n], acc[m][n], 0, 0, 0);
        __builtin_amdgcn_s_setprio(0);
        __syncthreads();
    }
    const int crq = (ln >> 4) * 4;
    #pragma unroll
    for (int m = 0; m < 4; ++m)
        #pragma unroll
        for (int n = 0; n < 4; ++n)
            #pragma unroll
            for (int r = 0; r < 4; ++r) {
                size_t idx = (size_t)(bm + wr * 64 + m * 16 + crq + r) * N
                             + bn + wc * 64 + n * 16 + lrow;
                if constexpr (std::is_same_v<OT, float>) C[idx] = acc[m][n][r];
                else C[idx] = f2bf(acc[m][n][r]);
            }
}

// ---------------- bf16 MFMA windowed flash attention -----------------------
// qkv: [B*L][3072] bf16 (Q at h*128, K at 2048+kh*128, V cols via vT);
// vT: [(b*4+kh)*128+dv][L]. Block: 64 q x (b,h); 4 waves x 16 q.
// T14 async-split staging + 2-deep LDS dbuf, single barrier per chunk.
__global__ __launch_bounds__(256) void attn_mfma(
        const unsigned short* __restrict__ qkv,
        const unsigned short* __restrict__ vT,
        unsigned short* __restrict__ ob) {
    __shared__ __attribute__((aligned(16))) unsigned short Ks[2][32 * 128];
    __shared__ __attribute__((aligned(16))) unsigned short VsT[2][128 * 40];

    const int t  = threadIdx.x;
    const int w  = t >> 6, l = t & 63;
    // work remap: each XCD owns one (b,kh) KV slab; long q-tiles first
    const int lin = blockIdx.y * gridDim.x + blockIdx.x;   // 0..1023
    const int wid = (lin & 7) * 128 + (lin >> 3);
    const int bh  = wid >> 5;
    const int qt  = 31 - (wid & 31);
    const int b  = bh >> 4, h = bh & 15;
    const int kh = h >> 2;
    const int i0 = qt * 64;
    const int iw = i0 + w * 16;          // wave's q base
    const int lq = l & 15;               // lane's q index (own query)
    const int g  = l >> 4;               // quad
    const int g8 = g * 8;
    const int i  = iw + lq;

    // staging thread roles (each thread: 2 K rows, 2 V rows)
    const int kr  = t >> 4;              // K row (this + kr+16)
    const int d8  = (t & 15) * 8;
    const int dv0 = t >> 2;              // V row (this + dv0+64)
    const int k8  = (t & 3) * 8;
    const unsigned short* kbase = qkv + (size_t)(b * L_) * QKVP_ + 2048 + kh * HD_;
    const unsigned short* vbase = vT + (size_t)((b * KVH_ + kh) * HD_) * L_;

    // Q fragments: lane holds Q[q=lq][d = dc*32 + g8 .. +8]
    bf16x8 qf[4];
    {
        const unsigned short* qrow = qkv + (size_t)(b * L_ + iw + lq) * QKVP_ + h * HD_;
        #pragma unroll
        for (int dc = 0; dc < 4; ++dc)
            qf[dc] = *reinterpret_cast<const bf16x8*>(qrow + dc * 32 + g8);
    }

    f32x4 oacc[8];
    const f32x4 z = {0.f, 0.f, 0.f, 0.f};
    #pragma unroll
    for (int c = 0; c < 8; ++c) oacc[c] = z;
    float mreg = -50000.f, lreg = 0.f;

    int jlo = i0 - WIN_; if (jlo < 0) jlo = 0;
    const int nch = (i0 + 64 - jlo) >> 5;
    const int wlo = iw - WIN_, whi = iw + 15;

    // prologue: stage chunk 0 into buf 0
    {
        const int jb = jlo;
        u16x8 k0 = *(const u16x8*)(kbase + (size_t)(jb + kr) * QKVP_ + d8);
        u16x8 k1 = *(const u16x8*)(kbase + (size_t)(jb + kr + 16) * QKVP_ + d8);
        u16x8 v0 = *(const u16x8*)(vbase + (size_t)dv0 * L_ + jb + k8);
        u16x8 v1 = *(const u16x8*)(vbase + (size_t)(dv0 + 64) * L_ + jb + k8);
        *(u16x8*)&Ks[0][kr * 128 + (d8 ^ ((kr & 7) << 3))] = k0;
        *(u16x8*)&Ks[0][(kr + 16) * 128 + (d8 ^ ((kr & 7) << 3))] = k1;
        *(u16x8*)&VsT[0][dv0 * 40 + k8] = v0;
        *(u16x8*)&VsT[0][(dv0 + 64) * 40 + k8] = v1;
    }
    __syncthreads();

    int cur = 0;
    for (int ch = 0; ch < nch; ++ch) {
        const int jb = jlo + ch * 32;
        const bool pre = (ch + 1 < nch);
        u16x8 k0, k1, v0, v1;
        if (pre) {   // T14: issue next chunk's loads before compute
            const int jn = jb + 32;
            k0 = *(const u16x8*)(kbase + (size_t)(jn + kr) * QKVP_ + d8);
            k1 = *(const u16x8*)(kbase + (size_t)(jn + kr + 16) * QKVP_ + d8);
            v0 = *(const u16x8*)(vbase + (size_t)dv0 * L_ + jn + k8);
            v1 = *(const u16x8*)(vbase + (size_t)(dv0 + 64) * L_ + jn + k8);
        }

        if (jb + 31 >= wlo && jb <= whi) {
            // ---- swapped QK^T: S^T tile kt, D: row=key=g*4+r, col=q=lq ----
            f32x4 st[2]; st[0] = z; st[1] = z;
            __builtin_amdgcn_s_setprio(1);
            #pragma unroll
            for (int kt = 0; kt < 2; ++kt) {
                const int krow = kt * 16 + lq;
                #pragma unroll
                for (int dc = 0; dc < 4; ++dc) {
                    bf16x8 kf = *reinterpret_cast<const bf16x8*>(
                        &Ks[cur][krow * 128 + ((dc * 32 + g8) ^ ((krow & 7) << 3))]);
                    st[kt] = __builtin_amdgcn_mfma_f32_16x16x32_bf16(
                        kf, qf[dc], st[kt], 0, 0, 0);
                }
            }
            __builtin_amdgcn_s_setprio(0);
            // ---- mask + online softmax (lane's 8 scores all for q = lq) ----
            float p8[2][4];
            float cmax = -1e30f;
            #pragma unroll
            for (int kt = 0; kt < 2; ++kt)
                #pragma unroll
                for (int r = 0; r < 4; ++r) {
                    const int j = jb + kt * 16 + g * 4 + r;
                    float s = st[kt][r] * SCALE_;
                    s = (j <= i && j >= i - WIN_) ? s : -1e30f;
                    p8[kt][r] = s;
                    cmax = fmaxf(cmax, s);
                }
            cmax = fmaxf(cmax, __shfl_xor(cmax, 16));
            cmax = fmaxf(cmax, __shfl_xor(cmax, 32));
            const bool noresc = __all(cmax - mreg <= 8.f);
            float alpha = 1.f;
            if (!noresc) {
                const float mnew = fmaxf(mreg, cmax);
                alpha = __expf(mreg - mnew);
                mreg = mnew;
            }
            float psum = 0.f;
            #pragma unroll
            for (int kt = 0; kt < 2; ++kt)
                #pragma unroll
                for (int r = 0; r < 4; ++r) {
                    const float p = __expf(p8[kt][r] - mreg);
                    p8[kt][r] = p; psum += p;
                }
            psum += __shfl_xor(psum, 16);
            psum += __shfl_xor(psum, 32);
            if (noresc) {
                lreg += psum;
            } else {
                lreg = lreg * alpha + psum;
                #pragma unroll
                for (int c = 0; c < 8; ++c)
                    #pragma unroll
                    for (int r = 0; r < 4; ++r) oacc[c][r] *= alpha;
            }
            // ---- P^T B-fragment via cross-lane shuffles (no LDS) ----
            const unsigned u00 = ((unsigned)f2bf(p8[0][1]) << 16) | f2bf(p8[0][0]);
            const unsigned u01 = ((unsigned)f2bf(p8[0][3]) << 16) | f2bf(p8[0][2]);
            const unsigned u10 = ((unsigned)f2bf(p8[1][1]) << 16) | f2bf(p8[1][0]);
            const unsigned u11 = ((unsigned)f2bf(p8[1][3]) << 16) | f2bf(p8[1][2]);
            union { unsigned u[4]; bf16x8 v; } pu;
            #pragma unroll
            for (int wd = 0; wd < 4; ++wd) {
                const int src = ((g & 1) * 2 + (wd >> 1)) * 16 + lq;
                const unsigned a0 = __shfl(wd & 1 ? u01 : u00, src);
                const unsigned a1 = __shfl(wd & 1 ? u11 : u10, src);
                pu.u[wd] = (g < 2) ? a0 : a1;
            }
            const bf16x8 pb = pu.v;
            // ---- PV: O^T = mfma(A = V^T-frag, B = P^T-frag) ----
            __builtin_amdgcn_s_setprio(1);
            #pragma unroll
            for (int c = 0; c < 8; ++c) {
                bf16x8 af = *reinterpret_cast<const bf16x8*>(
                    &VsT[cur][(c * 16 + lq) * 40 + g8]);
                oacc[c] = __builtin_amdgcn_mfma_f32_16x16x32_bf16(
                    af, pb, oacc[c], 0, 0, 0);
            }
            __builtin_amdgcn_s_setprio(0);
        }

        if (pre) {   // write-late into the other buffer (no barrier needed before)
            const int nb = cur ^ 1;
            *(u16x8*)&Ks[nb][kr * 128 + (d8 ^ ((kr & 7) << 3))] = k0;
            *(u16x8*)&Ks[nb][(kr + 16) * 128 + (d8 ^ ((kr & 7) << 3))] = k1;
            *(u16x8*)&VsT[nb][dv0 * 40 + k8] = v0;
            *(u16x8*)&VsT[nb][(dv0 + 64) * 40 + k8] = v1;
        }
        __syncthreads();
        cur ^= 1;
    }

    // ---- finalize: O[q=iw+lq][dv=c*16+g*4+r] /= l, store bf16 ----
    const float inv = 1.f / lreg;
    unsigned short* orow = ob + (size_t)(b * L_ + iw + lq) * E_ + h * HD_;
    #pragma unroll
    for (int c = 0; c < 8; ++c) {
        ushort4 o4;
        o4.x = f2bf(oacc[c][0] * inv);
        o4.y = f2bf(oacc[c][1] * inv);
        o4.z = f2bf(oacc[c][2] * inv);
        o4.w = f2bf(oacc[c][3] * inv);
        *reinterpret_cast<ushort4*>(&orow[c * 16 + g * 4]) = o4;
    }
}

extern "C" void kernel_launch(void* const* d_in, const int* in_sizes, int n_in,
                              void* d_out, int out_size, void* d_ws, size_t ws_size,
                              hipStream_t stream) {
    const float* x  = (const float*)d_in[0];
    const float* Wq = (const float*)d_in[1];
    const float* Wk = (const float*)d_in[2];
    const float* Wv = (const float*)d_in[3];
    const float* Wo = (const float*)d_in[4];
    float* out = (float*)d_out;

    const int M = B_ * L_;                      // 4096
    char* w = (char*)d_ws;
    unsigned short* qkv   = (unsigned short*)w; w += (size_t)M * QKVP_ * 2;  // 25.2 MB
    unsigned short* xb    = (unsigned short*)w; w += (size_t)M * E_ * 2;     // 16.8 MB (x bf16, then attn out)
    unsigned short* wqkvT = (unsigned short*)w; w += (size_t)QKVP_ * E_ * 2; // 12.6 MB
    unsigned short* wT1   = (unsigned short*)w; w += (size_t)E_ * E_ * 2;    // 8.4 MB (WoT)
    unsigned short* vTb   = (unsigned short*)w; w += (size_t)1024 * L_ * 2;  // 4.2 MB

    dim3 blk(256);

    conv_f32_bf16<<<dim3((M * E_ / 4 + 255) / 256), blk, 0, stream>>>(x, xb, M * E_ / 4);
    transpose_wqkv<<<dim3(QKVP_ / 32, E_ / 32), blk, 0, stream>>>(Wq, Wk, Wv, wqkvT);
    transpose_f32_bf16<<<dim3(E_ / 32, E_ / 32), blk, 0, stream>>>(Wo, wT1, E_, E_, E_);

    // fused QKV projection: [4096][3072]
    gemm_bt<unsigned short><<<dim3(QKVP_ / 128, M / 128), blk, 0, stream>>>(
        xb, wqkvT, qkv, M, QKVP_, E_);

    // V cols of qkv -> vT [(b*4+kh)*128+dv][L]
    transpose_v_bf16<<<dim3(512 / 32, M / 32), blk, 0, stream>>>(qkv, vTb);

    // attention writes bf16 directly into xb (its x-content is already consumed)
    attn_mfma<<<dim3(L_ / 64, B_ * H_), blk, 0, stream>>>(qkv, vTb, xb);

    gemm_bt<float><<<dim3(E_ / 128, M / 128), blk, 0, stream>>>(xb, wT1, out, M, E_, E_);
}